// Round 3
// baseline (178.319 us; speedup 1.0000x reference)
//
#include <hip/hip_runtime.h>

#define ALPHA 0.2f

typedef __attribute__((ext_vector_type(4))) short short4v;
typedef __attribute__((ext_vector_type(8))) short short8v;
typedef __attribute__((ext_vector_type(4))) float f32x4;

__device__ __forceinline__ short f2bf(float f) {
  union { float f; unsigned u; } v; v.f = f;
  unsigned r = v.u + 0x7fffu + ((v.u >> 16) & 1u);   // RNE to bf16
  return (short)(r >> 16);
}

// ------------------------------------------------------------------
// K1: h = x@W  -> hT (bf16, [64][8192]);  s1 = h@a1, s2 = h@a2 (fp32)
// ------------------------------------------------------------------
__global__ __launch_bounds__(256) void k1_proj(
    const float* __restrict__ x, const float* __restrict__ W,
    const float* __restrict__ avec,
    short* __restrict__ hT, float* __restrict__ s1, float* __restrict__ s2) {
  __shared__ float xl[32 * 132];
  __shared__ float Wl[128 * 64];
  const int t   = threadIdx.x;
  const int rb  = blockIdx.x;
  const int row = t >> 3;
  const int fg  = t & 7;
  float acc[8];
#pragma unroll
  for (int e = 0; e < 8; e++) acc[e] = 0.f;

  for (int kc = 0; kc < 4; kc++) {
#pragma unroll
    for (int u = 0; u < 4; u++) {
      int lin = t + u * 256;
      int r = lin >> 5, c4 = lin & 31;
      float4 v = *(const float4*)(x + (size_t)(rb * 32 + r) * 512 + kc * 128 + c4 * 4);
      *(float4*)(xl + r * 132 + c4 * 4) = v;
    }
#pragma unroll
    for (int u = 0; u < 8; u++) {
      int lin = t + u * 256;
      int r = lin >> 4, c4 = lin & 15;
      float4 v = *(const float4*)(W + (size_t)(kc * 128 + r) * 64 + c4 * 4);
      *(float4*)(Wl + r * 64 + c4 * 4) = v;
    }
    __syncthreads();
#pragma unroll 8
    for (int k = 0; k < 128; k++) {
      float xv = xl[row * 132 + k];
      float4 w0 = *(const float4*)(Wl + k * 64 + fg * 8);
      float4 w1 = *(const float4*)(Wl + k * 64 + fg * 8 + 4);
      acc[0] = fmaf(xv, w0.x, acc[0]); acc[1] = fmaf(xv, w0.y, acc[1]);
      acc[2] = fmaf(xv, w0.z, acc[2]); acc[3] = fmaf(xv, w0.w, acc[3]);
      acc[4] = fmaf(xv, w1.x, acc[4]); acc[5] = fmaf(xv, w1.y, acc[5]);
      acc[6] = fmaf(xv, w1.z, acc[6]); acc[7] = fmaf(xv, w1.w, acc[7]);
    }
    __syncthreads();
  }

  float p1 = 0.f, p2 = 0.f;
#pragma unroll
  for (int e = 0; e < 8; e++) {
    p1 = fmaf(acc[e], avec[fg * 8 + e], p1);
    p2 = fmaf(acc[e], avec[64 + fg * 8 + e], p2);
  }
  p1 += __shfl_xor(p1, 1, 64); p1 += __shfl_xor(p1, 2, 64); p1 += __shfl_xor(p1, 4, 64);
  p2 += __shfl_xor(p2, 1, 64); p2 += __shfl_xor(p2, 2, 64); p2 += __shfl_xor(p2, 4, 64);
  const int gi = rb * 32 + row;
  if (fg == 0) { s1[gi] = p1; s2[gi] = p2; }
#pragma unroll
  for (int e = 0; e < 8; e++)
    hT[(size_t)(fg * 8 + e) * 8192 + gi] = f2bf(acc[e]);
}

// ------------------------------------------------------------------
// K2 v3: chunk = 256 j-columns. Each adj load instruction reads ONE row
// x 1 KB contiguous (64 lanes x float4, wave-uniform row) -> full HBM
// page utilization. Wave owns 16 rows; tile held in 64 VGPRs; exp -> LDS
// (wave-private, no barriers); K=256 MFMA per chunk (8 k-steps x 4 fb).
// ------------------------------------------------------------------
__global__ __launch_bounds__(256, 3) void k2_attn(
    const float* __restrict__ adj, const short* __restrict__ hT,
    const float* __restrict__ s1, const float* __restrict__ s2,
    float* __restrict__ num, float* __restrict__ den,
    const int KS, const int JSPAN) {
  __shared__ short At[4][16][272];   // [wave][row][256+16 pad]
  const int t    = threadIdx.x;
  const int wvi  = t >> 6;
  const int l    = t & 63;
  const int lq   = l >> 4;           // 0..3
  const int lr   = l & 15;           // 0..15
  const int rb   = blockIdx.x & 127;
  const int ks   = blockIdx.x >> 7;
  const int r0   = rb << 6;
  const int j0   = ks * JSPAN;
  const int nchunk = JSPAN >> 8;     // chunks of 256

  // s1 for this wave's 16 rows -> uniform (SGPR)
  float s1r[16];
#pragma unroll
  for (int i = 0; i < 16; i++)
    s1r[i] = __int_as_float(
        __builtin_amdgcn_readfirstlane(__float_as_int(s1[r0 + wvi * 16 + i])));

  float denom_p[16];
#pragma unroll
  for (int i = 0; i < 16; i++) denom_p[i] = 0.f;

  f32x4 acc[4];
#pragma unroll
  for (int fb = 0; fb < 4; fb++) acc[fb] = (f32x4){0.f, 0.f, 0.f, 0.f};

  const float* arow0 = adj + (size_t)(r0 + wvi * 16) * 8192 + j0;

  for (int c = 0; c < nchunk; c++) {
    const int jc = j0 + c * 256;
    // ---- load adj tile: 16 rows x 1KB contiguous per instruction
    float4 av0,av1,av2,av3,av4,av5,av6,av7,av8,av9,av10,av11,av12,av13,av14,av15;
    {
      const float* ab = arow0 + c * 256 + l * 4;
      av0  = *(const float4*)(ab);
      av1  = *(const float4*)(ab + 1 * 8192);
      av2  = *(const float4*)(ab + 2 * 8192);
      av3  = *(const float4*)(ab + 3 * 8192);
      av4  = *(const float4*)(ab + 4 * 8192);
      av5  = *(const float4*)(ab + 5 * 8192);
      av6  = *(const float4*)(ab + 6 * 8192);
      av7  = *(const float4*)(ab + 7 * 8192);
      av8  = *(const float4*)(ab + 8 * 8192);
      av9  = *(const float4*)(ab + 9 * 8192);
      av10 = *(const float4*)(ab + 10 * 8192);
      av11 = *(const float4*)(ab + 11 * 8192);
      av12 = *(const float4*)(ab + 12 * 8192);
      av13 = *(const float4*)(ab + 13 * 8192);
      av14 = *(const float4*)(ab + 14 * 8192);
      av15 = *(const float4*)(ab + 15 * 8192);
    }
    float4 s2v = *(const float4*)(s2 + jc + l * 4);

#define K2_EXPROW(I, AV) do {                                                 \
      float z0 = s1r[I] + s2v.x; z0 = fmaxf(z0, ALPHA * z0) * AV.x;           \
      float z1 = s1r[I] + s2v.y; z1 = fmaxf(z1, ALPHA * z1) * AV.y;           \
      float z2 = s1r[I] + s2v.z; z2 = fmaxf(z2, ALPHA * z2) * AV.z;           \
      float z3 = s1r[I] + s2v.w; z3 = fmaxf(z3, ALPHA * z3) * AV.w;           \
      float w0 = __expf(z0), w1 = __expf(z1), w2 = __expf(z2), w3 = __expf(z3);\
      denom_p[I] += (w0 + w1) + (w2 + w3);                                    \
      short4v pk = { f2bf(w0), f2bf(w1), f2bf(w2), f2bf(w3) };                \
      *(short4v*)(&At[wvi][I][l * 4]) = pk;                                   \
    } while (0)

    K2_EXPROW(0, av0);   K2_EXPROW(1, av1);   K2_EXPROW(2, av2);
    K2_EXPROW(3, av3);   K2_EXPROW(4, av4);   K2_EXPROW(5, av5);
    K2_EXPROW(6, av6);   K2_EXPROW(7, av7);   K2_EXPROW(8, av8);
    K2_EXPROW(9, av9);   K2_EXPROW(10, av10); K2_EXPROW(11, av11);
    K2_EXPROW(12, av12); K2_EXPROW(13, av13); K2_EXPROW(14, av14);
    K2_EXPROW(15, av15);
#undef K2_EXPROW

    // ---- MFMA: K=256 against hT (L2-resident)
#pragma unroll
    for (int kk = 0; kk < 8; kk++) {
      const int k0 = kk * 32;
      union { short4v h[2]; short8v v; } au, bu;
      au.h[0] = *(const short4v*)(&At[wvi][lr][k0 + lq * 4]);
      au.h[1] = *(const short4v*)(&At[wvi][lr][k0 + 16 + lq * 4]);
#pragma unroll
      for (int fb = 0; fb < 4; fb++) {
        const short* bp = hT + (size_t)(fb * 16 + lr) * 8192 + jc + k0 + lq * 4;
        bu.h[0] = *(const short4v*)(bp);
        bu.h[1] = *(const short4v*)(bp + 16);
        acc[fb] = __builtin_amdgcn_mfma_f32_16x16x32_bf16(au.v, bu.v,
                                                          acc[fb], 0, 0, 0);
      }
    }
  }

  // ---- epilogue: denominators (reduce 16 rows across 64 lanes)
#pragma unroll
  for (int i = 0; i < 16; i++) {
    float d = denom_p[i];
    d += __shfl_xor(d, 1, 64); d += __shfl_xor(d, 2, 64);
    d += __shfl_xor(d, 4, 64); d += __shfl_xor(d, 8, 64);
    d += __shfl_xor(d, 16, 64); d += __shfl_xor(d, 32, 64);
    if (l == 0) den[(size_t)ks * 8192 + r0 + wvi * 16 + i] = d;
  }
  float* np = num + (size_t)ks * 524288;
#pragma unroll
  for (int fb = 0; fb < 4; fb++)
#pragma unroll
    for (int r = 0; r < 4; r++)
      np[(size_t)(r0 + wvi * 16 + lq * 4 + r) * 64 + fb * 16 + lr] = acc[fb][r];
}

// ------------------------------------------------------------------
// K3: out = elu( sum_ks num / sum_ks den )
// ------------------------------------------------------------------
__global__ __launch_bounds__(256) void k3_norm(
    const float* __restrict__ num, const float* __restrict__ den,
    float* __restrict__ out, const int KS) {
  const int idx = blockIdx.x * 256 + threadIdx.x;   // 0..524287
  const int row = idx >> 6;
  float n = 0.f, d = 0.f;
  for (int ksi = 0; ksi < KS; ksi++) {
    n += num[(size_t)ksi * 524288 + idx];
    d += den[ksi * 8192 + row];
  }
  float v = n / d;
  out[idx] = v > 0.f ? v : (__expf(v) - 1.f);
}

extern "C" void kernel_launch(void* const* d_in, const int* in_sizes, int n_in,
                              void* d_out, int out_size, void* d_ws, size_t ws_size,
                              hipStream_t stream) {
  const float* x   = (const float*)d_in[0];
  const float* adj = (const float*)d_in[1];
  const float* W   = (const float*)d_in[2];
  const float* av  = (const float*)d_in[3];
  float* out = (float*)d_out;
  char* ws = (char*)d_ws;

  short* hT = (short*)ws;                                  // 1 MB
  float* s1 = (float*)(ws + (1 << 20));                    // 32 KB
  float* s2 = (float*)(ws + (1 << 20) + 32768);            // 32 KB
  float* num = (float*)(ws + (1 << 20) + 65536);
  int KS = 8;
  while (KS > 1) {
    size_t need = (size_t)(1 << 20) + 65536 + (size_t)KS * (524288u * 4u + 32768u);
    if (need <= ws_size) break;
    KS >>= 1;
  }
  float* den = num + (size_t)KS * 524288;

  hipLaunchKernelGGL(k1_proj, dim3(256), dim3(256), 0, stream, x, W, av, hT, s1, s2);
  hipLaunchKernelGGL(k2_attn, dim3(128 * KS), dim3(256), 0, stream,
                     adj, hT, s1, s2, num, den, KS, 8192 / KS);
  hipLaunchKernelGGL(k3_norm, dim3(2048), dim3(256), 0, stream, num, den, out, KS);
}